// Round 11
// baseline (125.088 us; speedup 1.0000x reference)
//
#include <hip/hip_runtime.h>
#include <hip/hip_bf16.h>

// Problem: B=4, C=19, H=1024, W=1024, N=500000
// out = mean_n [ log(sum_j exp(p_j)) - p_label ],  p = softmax(predict[b,:,r,c])
//
// Round-11 = round-10 (best, 85.0us: LDS-tiled TILE=256 kernel A, full
// occupancy) + two byte/overhead shavings:
//   1. table stored as bf16 (8MB not 16MB): -8MB write in A, -~8MB random
//      line footprint in B. nll in [~2,4], bf16 RNE err <= 0.008/sample,
//      mean bias << threshold 0.059.
//   2. finalize fused into B via last-block ticket (partial -> threadfence ->
//      atomicAdd(ticket); last block re-reduces all partials in FIXED index
//      order with double accum -> deterministic). Ticket zeroed by A each
//      call (graph-replay safe).
//
// Lessons kept: NO mask/predication (R7/R8), NO register-array float4 (R5/R6
// VGPR cliff), NO nontemporal hints (R5), NO random scatter atomics (R8),
// TILE=256 not 512 (R9 occupancy cliff), integer inputs arrive int32 (R1).

#define CCH 19
#define BLOCK 256
#define TILE 256                  // positions per block tile (= BLOCK)
#define POS_BITS 20               // H*W = 1<<20
#define TOTAL_POS (4 << POS_BITS) // B * H * W = 4M
#define NV4 (CCH * TILE / 4)      // 1216 float4 loads per tile

__device__ __forceinline__ float nll_compute(float* __restrict__ x, int label)
{
    float m = x[0];
    #pragma unroll
    for (int j = 1; j < CCH; ++j) m = fmaxf(m, x[j]);

    float s = 0.0f, e_label = 0.0f;
    #pragma unroll
    for (int j = 0; j < CCH; ++j) {
        float e = __expf(x[j] - m);
        s += e;
        if (j == label) e_label = e;   // static j vs runtime label -> cndmask
        x[j] = e;
    }
    float inv = 1.0f / s;

    float s2 = 0.0f;
    #pragma unroll
    for (int j = 0; j < CCH; ++j) s2 += __expf(x[j] * inv);

    return __logf(s2) - e_label * inv;
}

// ---- kernel A: LDS-tiled bf16 nll table, 19KB LDS, full occupancy ----
__global__ __launch_bounds__(BLOCK) void nll_table_tiled256(
    const float* __restrict__ predict,
    const int* __restrict__ target,
    __hip_bfloat16* __restrict__ table,
    unsigned int* __restrict__ ticket)
{
    if (blockIdx.x == 0 && threadIdx.x == 0) *ticket = 0u;  // replay-safe reset

    __shared__ float lds[CCH * TILE];              // 19 KB -> 8 blocks/CU
    int i0 = blockIdx.x * TILE;                    // flat position base
    int b = i0 >> POS_BITS;
    int pos0 = i0 & ((1 << POS_BITS) - 1);
    const float* pbase = predict + (((size_t)b * CCH) << POS_BITS) + (size_t)pos0;

    // stage 19 channels x 256 floats: one 1KB contiguous float4 burst/channel
    #pragma unroll
    for (int it = 0; it < (NV4 + BLOCK - 1) / BLOCK; ++it) {
        int f = it * BLOCK + threadIdx.x;          // float4 slot in [0, 1216)
        if (f < NV4) {
            int ch = f >> 6;                       // 64 float4 per channel
            int q  = f & 63;
            float4 v = *(const float4*)(pbase + ((size_t)ch << POS_BITS) + (q << 2));
            *(float4*)&lds[ch * TILE + (q << 2)] = v;
        }
    }
    __syncthreads();

    // 1 position per thread; LDS reads lane-stride-4B (2-way aliasing = free)
    int pp = threadIdx.x;
    float x[CCH];
    #pragma unroll
    for (int j = 0; j < CCH; ++j) x[j] = lds[j * TILE + pp];
    table[i0 + pp] = __float2bfloat16(nll_compute(x, target[i0 + pp]));
}

// ---- kernel B: random 2B gather from bf16 table + block reduce + fused
//      last-block finalize (deterministic: fixed-order double accumulation) ----
__global__ __launch_bounds__(BLOCK) void table_gather_finalize(
    const __hip_bfloat16* __restrict__ table,
    const int* __restrict__ loc_b,
    const int* __restrict__ loc_row,
    const int* __restrict__ loc_col,
    float* __restrict__ partial,
    unsigned int* __restrict__ ticket,
    float* __restrict__ out,
    int n, float inv_n)
{
    int i = blockIdx.x * blockDim.x + threadIdx.x;
    float nll = 0.0f;
    if (i < n) {
        int idx = (loc_b[i] << POS_BITS) + (loc_row[i] << 10) + loc_col[i];
        nll = __bfloat162float(table[idx]);
    }
    __shared__ float red[BLOCK];
    red[threadIdx.x] = nll;
    __syncthreads();
    #pragma unroll
    for (int off = BLOCK / 2; off > 0; off >>= 1) {
        if (threadIdx.x < off) red[threadIdx.x] += red[threadIdx.x + off];
        __syncthreads();
    }

    __shared__ unsigned int is_last;
    if (threadIdx.x == 0) {
        partial[blockIdx.x] = red[0];
        __threadfence();                               // publish partial
        unsigned int t = atomicAdd(ticket, 1u);        // device-scope
        is_last = (t == gridDim.x - 1) ? 1u : 0u;
    }
    __syncthreads();

    if (is_last) {
        __threadfence();                               // acquire all partials
        double acc = 0.0;
        for (int k = threadIdx.x; k < (int)gridDim.x; k += BLOCK)
            acc += (double)partial[k];                 // fixed order per thread
        __shared__ double dred[BLOCK];
        dred[threadIdx.x] = acc;
        __syncthreads();
        #pragma unroll
        for (int off = BLOCK / 2; off > 0; off >>= 1) {
            if (threadIdx.x < off) dred[threadIdx.x] += dred[threadIdx.x + off];
            __syncthreads();
        }
        if (threadIdx.x == 0) out[0] = (float)(dred[0] * (double)inv_n);
    }
}

// ---- fallback: direct random gather (round-2 path), used if ws too small ----
__global__ __launch_bounds__(BLOCK) void partial_loss_gather(
    const float* __restrict__ predict,
    const int* __restrict__ target,
    const int* __restrict__ loc_b,
    const int* __restrict__ loc_row,
    const int* __restrict__ loc_col,
    float* __restrict__ partial,
    int n)
{
    int i = blockIdx.x * blockDim.x + threadIdx.x;
    float nll = 0.0f;
    if (i < n) {
        int b = loc_b[i];
        int pos = (loc_row[i] << 10) + loc_col[i];
        const float* base = predict + (((size_t)b * CCH) << POS_BITS) + (size_t)pos;
        int label = target[((size_t)b << POS_BITS) + (size_t)pos];
        float x[CCH];
        #pragma unroll
        for (int j = 0; j < CCH; ++j) x[j] = base[(size_t)j << POS_BITS];
        nll = nll_compute(x, label);
    }
    __shared__ float red[BLOCK];
    red[threadIdx.x] = nll;
    __syncthreads();
    #pragma unroll
    for (int off = BLOCK / 2; off > 0; off >>= 1) {
        if (threadIdx.x < off) red[threadIdx.x] += red[threadIdx.x + off];
        __syncthreads();
    }
    if (threadIdx.x == 0) partial[blockIdx.x] = red[0];
}

__global__ __launch_bounds__(BLOCK) void partial_loss_finalize(
    const float* __restrict__ partial,
    int nparts,
    float* __restrict__ out,
    float inv_n)
{
    __shared__ double red[BLOCK];
    double acc = 0.0;
    for (int i = threadIdx.x; i < nparts; i += BLOCK) acc += (double)partial[i];
    red[threadIdx.x] = acc;
    __syncthreads();
    #pragma unroll
    for (int off = BLOCK / 2; off > 0; off >>= 1) {
        if (threadIdx.x < off) red[threadIdx.x] += red[threadIdx.x + off];
        __syncthreads();
    }
    if (threadIdx.x == 0) out[0] = (float)(red[0] * (double)inv_n);
}

extern "C" void kernel_launch(void* const* d_in, const int* in_sizes, int n_in,
                              void* d_out, int out_size, void* d_ws, size_t ws_size,
                              hipStream_t stream)
{
    const float* predict = (const float*)d_in[0];
    const int*   target  = (const int*)d_in[1];
    const int*   loc_b   = (const int*)d_in[2];
    const int*   loc_row = (const int*)d_in[3];
    const int*   loc_col = (const int*)d_in[4];
    float* out = (float*)d_out;

    int n = in_sizes[2];                         // N = 500000
    int nblocks = (n + BLOCK - 1) / BLOCK;       // 1954

    size_t table_bytes   = (size_t)TOTAL_POS * sizeof(__hip_bfloat16);  // 8 MB
    size_t partial_bytes = (size_t)((nblocks + 63) & ~63) * sizeof(float);

    if (ws_size >= table_bytes + partial_bytes + sizeof(unsigned int)) {
        __hip_bfloat16* table   = (__hip_bfloat16*)d_ws;
        float*          partial = (float*)((char*)d_ws + table_bytes);
        unsigned int*   ticket  =
            (unsigned int*)((char*)d_ws + table_bytes + partial_bytes);

        nll_table_tiled256<<<TOTAL_POS / TILE, BLOCK, 0, stream>>>(
            predict, target, table, ticket);
        table_gather_finalize<<<nblocks, BLOCK, 0, stream>>>(
            table, loc_b, loc_row, loc_col, partial, ticket, out,
            n, 1.0f / (float)n);
    } else {
        float* partial = (float*)d_ws;
        partial_loss_gather<<<nblocks, BLOCK, 0, stream>>>(
            predict, target, loc_b, loc_row, loc_col, partial, n);
        partial_loss_finalize<<<1, BLOCK, 0, stream>>>(
            partial, nblocks, out, 1.0f / (float)n);
    }
}

// Round 12
// 82.482 us; speedup vs baseline: 1.5166x; 1.5166x over previous
//
#include <hip/hip_runtime.h>
#include <hip/hip_bf16.h>

// Problem: B=4, C=19, H=1024, W=1024, N=500000
// out = mean_n [ log(sum_j exp(p_j)) - p_label ],  p = softmax(predict[b,:,r,c])
//
// Round-12 = round-10 base (85.0us: LDS-tiled TILE=256 kernel A @ full
// occupancy, separate gather + finalize kernels) + ONE change: bf16 table.
//   - A writes 8MB instead of 16MB; B's random-gather footprint halves.
//   - R11's ticket/threadfence fused finalize is REVERTED: 1954 same-address
//     device-scope atomics serialize at the coherence point (cross-XCD line
//     ping-pong) and cost way more than the ~4us launch savings. Generalizes
//     R8's lesson: contended/random atomics are poison on this chip.
//
// Lessons kept: NO mask/predication (R7/R8), NO register-array float4 (R5/R6
// VGPR cliff), NO nontemporal hints (R5), NO atomics of any kind (R8/R11),
// TILE=256 not 512 at BLOCK=256 (R9 occupancy cliff), ints arrive int32 (R1).

#define CCH 19
#define BLOCK 256
#define TILE 256                  // positions per block tile (= BLOCK)
#define POS_BITS 20               // H*W = 1<<20
#define TOTAL_POS (4 << POS_BITS) // B * H * W = 4M
#define NV4 (CCH * TILE / 4)      // 1216 float4 loads per tile

__device__ __forceinline__ float nll_compute(float* __restrict__ x, int label)
{
    float m = x[0];
    #pragma unroll
    for (int j = 1; j < CCH; ++j) m = fmaxf(m, x[j]);

    float s = 0.0f, e_label = 0.0f;
    #pragma unroll
    for (int j = 0; j < CCH; ++j) {
        float e = __expf(x[j] - m);
        s += e;
        if (j == label) e_label = e;   // static j vs runtime label -> cndmask
        x[j] = e;
    }
    float inv = 1.0f / s;

    float s2 = 0.0f;
    #pragma unroll
    for (int j = 0; j < CCH; ++j) s2 += __expf(x[j] * inv);

    return __logf(s2) - e_label * inv;
}

// ---- kernel A: LDS-tiled bf16 nll table, 19KB LDS, full occupancy ----
// grid = TOTAL_POS/TILE = 16384 blocks; TILE divides H*W so a tile never
// straddles the batch dimension.
__global__ __launch_bounds__(BLOCK) void nll_table_tiled256(
    const float* __restrict__ predict,
    const int* __restrict__ target,
    __hip_bfloat16* __restrict__ table)
{
    __shared__ float lds[CCH * TILE];              // 19 KB -> 8 blocks/CU
    int i0 = blockIdx.x * TILE;                    // flat position base
    int b = i0 >> POS_BITS;
    int pos0 = i0 & ((1 << POS_BITS) - 1);
    const float* pbase = predict + (((size_t)b * CCH) << POS_BITS) + (size_t)pos0;

    // stage 19 channels x 256 floats: one 1KB contiguous float4 burst/channel
    #pragma unroll
    for (int it = 0; it < (NV4 + BLOCK - 1) / BLOCK; ++it) {
        int f = it * BLOCK + threadIdx.x;          // float4 slot in [0, 1216)
        if (f < NV4) {
            int ch = f >> 6;                       // 64 float4 per channel
            int q  = f & 63;
            float4 v = *(const float4*)(pbase + ((size_t)ch << POS_BITS) + (q << 2));
            *(float4*)&lds[ch * TILE + (q << 2)] = v;
        }
    }
    __syncthreads();

    // 1 position per thread; LDS reads lane-stride-4B (2-way aliasing = free)
    int pp = threadIdx.x;
    float x[CCH];
    #pragma unroll
    for (int j = 0; j < CCH; ++j) x[j] = lds[j * TILE + pp];
    table[i0 + pp] = __float2bfloat16(nll_compute(x, target[i0 + pp]));
}

// ---- kernel B: random 2B gather from bf16 table + block reduce ----
__global__ __launch_bounds__(BLOCK) void table_gather_kernel(
    const __hip_bfloat16* __restrict__ table,
    const int* __restrict__ loc_b,
    const int* __restrict__ loc_row,
    const int* __restrict__ loc_col,
    float* __restrict__ partial,
    int n)
{
    int i = blockIdx.x * blockDim.x + threadIdx.x;
    float nll = 0.0f;
    if (i < n) {
        int idx = (loc_b[i] << POS_BITS) + (loc_row[i] << 10) + loc_col[i];
        nll = __bfloat162float(table[idx]);
    }
    __shared__ float red[BLOCK];
    red[threadIdx.x] = nll;
    __syncthreads();
    #pragma unroll
    for (int off = BLOCK / 2; off > 0; off >>= 1) {
        if (threadIdx.x < off) red[threadIdx.x] += red[threadIdx.x + off];
        __syncthreads();
    }
    if (threadIdx.x == 0) partial[blockIdx.x] = red[0];
}

// ---- fallback: direct random gather (round-2 path), used if ws too small ----
__global__ __launch_bounds__(BLOCK) void partial_loss_gather(
    const float* __restrict__ predict,
    const int* __restrict__ target,
    const int* __restrict__ loc_b,
    const int* __restrict__ loc_row,
    const int* __restrict__ loc_col,
    float* __restrict__ partial,
    int n)
{
    int i = blockIdx.x * blockDim.x + threadIdx.x;
    float nll = 0.0f;
    if (i < n) {
        int b = loc_b[i];
        int pos = (loc_row[i] << 10) + loc_col[i];
        const float* base = predict + (((size_t)b * CCH) << POS_BITS) + (size_t)pos;
        int label = target[((size_t)b << POS_BITS) + (size_t)pos];
        float x[CCH];
        #pragma unroll
        for (int j = 0; j < CCH; ++j) x[j] = base[(size_t)j << POS_BITS];
        nll = nll_compute(x, label);
    }
    __shared__ float red[BLOCK];
    red[threadIdx.x] = nll;
    __syncthreads();
    #pragma unroll
    for (int off = BLOCK / 2; off > 0; off >>= 1) {
        if (threadIdx.x < off) red[threadIdx.x] += red[threadIdx.x + off];
        __syncthreads();
    }
    if (threadIdx.x == 0) partial[blockIdx.x] = red[0];
}

__global__ __launch_bounds__(BLOCK) void partial_loss_finalize(
    const float* __restrict__ partial,
    int nparts,
    float* __restrict__ out,
    float inv_n)
{
    __shared__ double red[BLOCK];
    double acc = 0.0;
    for (int i = threadIdx.x; i < nparts; i += BLOCK) acc += (double)partial[i];
    red[threadIdx.x] = acc;
    __syncthreads();
    #pragma unroll
    for (int off = BLOCK / 2; off > 0; off >>= 1) {
        if (threadIdx.x < off) red[threadIdx.x] += red[threadIdx.x + off];
        __syncthreads();
    }
    if (threadIdx.x == 0) out[0] = (float)(red[0] * (double)inv_n);
}

extern "C" void kernel_launch(void* const* d_in, const int* in_sizes, int n_in,
                              void* d_out, int out_size, void* d_ws, size_t ws_size,
                              hipStream_t stream)
{
    const float* predict = (const float*)d_in[0];
    const int*   target  = (const int*)d_in[1];
    const int*   loc_b   = (const int*)d_in[2];
    const int*   loc_row = (const int*)d_in[3];
    const int*   loc_col = (const int*)d_in[4];
    float* out = (float*)d_out;

    int n = in_sizes[2];                         // N = 500000
    int nblocks = (n + BLOCK - 1) / BLOCK;       // 1954

    size_t table_bytes   = (size_t)TOTAL_POS * sizeof(__hip_bfloat16);  // 8 MB
    size_t partial_bytes = (size_t)nblocks * sizeof(float);

    if (ws_size >= table_bytes + partial_bytes) {
        __hip_bfloat16* table   = (__hip_bfloat16*)d_ws;
        float*          partial = (float*)((char*)d_ws + table_bytes);

        nll_table_tiled256<<<TOTAL_POS / TILE, BLOCK, 0, stream>>>(
            predict, target, table);
        table_gather_kernel<<<nblocks, BLOCK, 0, stream>>>(
            table, loc_b, loc_row, loc_col, partial, n);
        partial_loss_finalize<<<1, BLOCK, 0, stream>>>(
            partial, nblocks, out, 1.0f / (float)n);
    } else {
        float* partial = (float*)d_ws;
        partial_loss_gather<<<nblocks, BLOCK, 0, stream>>>(
            predict, target, loc_b, loc_row, loc_col, partial, n);
        partial_loss_finalize<<<1, BLOCK, 0, stream>>>(
            partial, nblocks, out, 1.0f / (float)n);
    }
}